// Round 2
// baseline (427.721 us; speedup 1.0000x reference)
//
#include <hip/hip_runtime.h>
#include <hip/hip_bf16.h>

// out[m][n] = C[m][n] * D[n];  M = NR = 8192, fp32 in/out.
// Memory-bound column scaling. Each thread loads its D float4 ONCE and
// streams 32 rows of C with nontemporal float4 loads/stores (once-touched
// 512 MiB working set -> skip LLC allocate).

#define NR     8192
#define M_ROWS 8192
#define NR4    (NR / 4)     // 2048 float4 per row
#define ROWS_PT 32          // rows per thread

typedef float v4f __attribute__((ext_vector_type(4)));

__global__ __launch_bounds__(256) void colscale_kernel(
    const v4f* __restrict__ C4,
    const v4f* __restrict__ D4,
    v4f* __restrict__ O4)
{
    // blockIdx.x in [0,8): column float4 group; blockIdx.y in [0,256): row strip
    const unsigned c4   = blockIdx.x * 256u + threadIdx.x;          // [0, 2048)
    const unsigned base = blockIdx.y * (ROWS_PT * NR4) + c4;

    const v4f d = D4[c4];   // one load, reused for 32 rows (L1/L2 resident)

#pragma unroll 8
    for (int r = 0; r < ROWS_PT; ++r) {
        const unsigned idx = base + (unsigned)r * NR4;
        v4f c = __builtin_nontemporal_load(&C4[idx]);
        v4f o = c * d;
        __builtin_nontemporal_store(o, &O4[idx]);
    }
}

extern "C" void kernel_launch(void* const* d_in, const int* in_sizes, int n_in,
                              void* d_out, int out_size, void* d_ws, size_t ws_size,
                              hipStream_t stream) {
    const v4f* C4 = (const v4f*)d_in[0];
    const v4f* D4 = (const v4f*)d_in[1];
    v4f* O4 = (v4f*)d_out;

    dim3 grid(NR4 / 256, M_ROWS / ROWS_PT);   // (8, 256) = 2048 blocks
    dim3 block(256);

    colscale_kernel<<<grid, block, 0, stream>>>(C4, D4, O4);
}